// Round 8
// baseline (439.156 us; speedup 1.0000x reference)
//
#include <hip/hip_runtime.h>
#include <stdint.h>

#define T_SEQ 2048
#define NH 16
#define HD 64
#define DM 1024
#define BB 4
#define MROWS (BB * T_SEQ)   // 8192

typedef __attribute__((ext_vector_type(8))) __bf16 bf16x8;
typedef __attribute__((ext_vector_type(8))) unsigned short u16x8;
typedef __attribute__((ext_vector_type(4))) unsigned short u16x4;
typedef __attribute__((ext_vector_type(4))) float f32x4;

__device__ __forceinline__ unsigned short f2bf(float f) {
  unsigned int x = __float_as_uint(f);
  x = (x + 0x7fffu + ((x >> 16) & 1u)) >> 16;  // RNE
  return (unsigned short)x;
}

__device__ __forceinline__ bf16x8 ld8_f32(const float* __restrict__ p) {
  f32x4 a = *(const f32x4*)p;
  f32x4 b = *(const f32x4*)(p + 4);
  u16x8 u;
#pragma unroll
  for (int i = 0; i < 4; ++i) {
    u[i]     = f2bf(a[i]);
    u[i + 4] = f2bf(b[i]);
  }
  return __builtin_bit_cast(bf16x8, u);
}

__device__ __forceinline__ bf16x8 ld8_bf(const unsigned short* p) {
  return __builtin_bit_cast(bf16x8, *(const u16x8*)p);
}

// 8-aligned LDS read as two b64s (stride-68 layouts are not 16B-aligned)
__device__ __forceinline__ bf16x8 ld8_lds(const unsigned short* p) {
  u16x4 a = *(const u16x4*)p;
  u16x4 b = *(const u16x4*)(p + 4);
  return __builtin_bit_cast(bf16x8,
      __builtin_shufflevector(a, b, 0, 1, 2, 3, 4, 5, 6, 7));
}

__device__ __forceinline__ u16x4 lo4(u16x8 v) {
  return __builtin_shufflevector(v, v, 0, 1, 2, 3);
}
__device__ __forceinline__ u16x4 hi4(u16x8 v) {
  return __builtin_shufflevector(v, v, 4, 5, 6, 7);
}

__device__ __forceinline__ void gload_lds16(const unsigned short* g,
                                            unsigned short* l) {
  __builtin_amdgcn_global_load_lds(
      (const __attribute__((address_space(1))) unsigned int*)g,
      (__attribute__((address_space(3))) unsigned int*)l, 16, 0, 0);
}

// ---------------------------------------------------------------------------
// fp32 -> bf16 elementwise (8 elems/thread).
// ---------------------------------------------------------------------------
__global__ __launch_bounds__(256) void conv_f32_bf16(
    const float* __restrict__ src, unsigned short* __restrict__ dst, int n8) {
  const int i = blockIdx.x * 256 + threadIdx.x;
  if (i < n8)
    *(u16x8*)(dst + (size_t)i * 8) =
        __builtin_bit_cast(u16x8, ld8_f32(src + (size_t)i * 8));
}

// ---------------------------------------------------------------------------
// m97-style bf16 GEMM: C = A[M,K] @ B[N,K]^T. 128x128 tile, BK=32,
// global_load_lds width=16. MODE 0: bf16 row-major out. MODE 1: f32
// row-major out. MODE 2: bf16 out transposed to Vt[b][h][d][t] (b64-packed).
// ---------------------------------------------------------------------------
template <int MODE>
__global__ __launch_bounds__(256) void gemm128(
    const unsigned short* __restrict__ A, const unsigned short* __restrict__ B,
    void* __restrict__ Cv, int M, int N, int K) {
  __shared__ __align__(16) unsigned short As[128 * 32];
  __shared__ __align__(16) unsigned short Bs[128 * 32];

  const int t = threadIdx.x;
  const int lane = t & 63, wave = t >> 6;
  const int m0 = blockIdx.y * 128, n0 = blockIdx.x * 128;

  const int srow = t >> 2;
  const int scol = (t & 3) * 8;
  const unsigned short* ga0 = A + (size_t)(m0 + srow) * K + scol;
  const unsigned short* ga1 = A + (size_t)(m0 + 64 + srow) * K + scol;
  const unsigned short* gb0 = B + (size_t)(n0 + srow) * K + scol;
  const unsigned short* gb1 = B + (size_t)(n0 + 64 + srow) * K + scol;
  unsigned short* lA0 = &As[(wave * 16) * 32];
  unsigned short* lA1 = &As[(64 + wave * 16) * 32];
  unsigned short* lB0 = &Bs[(wave * 16) * 32];
  unsigned short* lB1 = &Bs[(64 + wave * 16) * 32];

  const int mw = (wave >> 1) * 64, nw = (wave & 1) * 64;
  const int fr = lane & 15, fq = (lane >> 4) * 8;

  f32x4 acc[4][4];
#pragma unroll
  for (int i = 0; i < 4; ++i)
#pragma unroll
    for (int j = 0; j < 4; ++j) acc[i][j] = (f32x4){0.f, 0.f, 0.f, 0.f};

  for (int k0 = 0; k0 < K; k0 += 32) {
    __syncthreads();
    gload_lds16(ga0 + k0, lA0);
    gload_lds16(ga1 + k0, lA1);
    gload_lds16(gb0 + k0, lB0);
    gload_lds16(gb1 + k0, lB1);
    __syncthreads();

    bf16x8 af[4], bfr[4];
#pragma unroll
    for (int i = 0; i < 4; ++i)
      af[i] = ld8_bf(&As[(mw + i * 16 + fr) * 32 + fq]);
#pragma unroll
    for (int j = 0; j < 4; ++j)
      bfr[j] = ld8_bf(&Bs[(nw + j * 16 + fr) * 32 + fq]);
#pragma unroll
    for (int i = 0; i < 4; ++i)
#pragma unroll
      for (int j = 0; j < 4; ++j)
        acc[i][j] = __builtin_amdgcn_mfma_f32_16x16x32_bf16(af[i], bfr[j],
                                                            acc[i][j], 0, 0, 0);
  }

  const int orow = (lane >> 4) * 4, ocol = lane & 15;
#pragma unroll
  for (int i = 0; i < 4; ++i)
#pragma unroll
    for (int j = 0; j < 4; ++j) {
      if constexpr (MODE == 2) {
        const int mb = m0 + mw + i * 16 + orow;
        const int n = n0 + nw + j * 16 + ocol;
        u16x4 pk;
#pragma unroll
        for (int r = 0; r < 4; ++r) pk[r] = f2bf(acc[i][j][r]);
        unsigned short* dst = (unsigned short*)Cv +
            ((size_t)((mb >> 11) * NH + (n >> 6)) * HD + (n & 63)) * T_SEQ +
            (mb & 2047);
        *(u16x4*)dst = pk;
      } else {
#pragma unroll
        for (int r = 0; r < 4; ++r) {
          const size_t idx = (size_t)(m0 + mw + i * 16 + orow + r) * N +
                             (n0 + nw + j * 16 + ocol);
          if constexpr (MODE == 1)
            ((float*)Cv)[idx] = acc[i][j][r];
          else
            ((unsigned short*)Cv)[idx] = f2bf(acc[i][j][r]);
        }
      }
    }
}

// ---------------------------------------------------------------------------
// MFMA flash attention v3 (causal). Same math/layout as v2 (validated R7:
// S^T = K@Q^T, Vt pre-transposed, stride-68 LDS, 0 bank conflicts). New:
//  - register prefetch double-buffer: tile t+1's K/Vt global loads issue
//    before tile t's compute -> HBM/L2 latency overlapped (was serialized
//    in the 2-barrier loop: ~5.9k cyc/wave-tile vs ~800 compute).
//  - XCD-locality swizzle: same-(b,h) blocks share linear-id mod 8 (one
//    XCD under round-robin) so K/Vt stay L2-resident; heavy qt first.
// ---------------------------------------------------------------------------
#define ASTR 68

__global__ __launch_bounds__(256, 4) void attn_flash3(
    const unsigned short* Qw, const unsigned short* __restrict__ Kw,
    const unsigned short* __restrict__ Vt, unsigned short* Ow) {
  __shared__ __align__(16) unsigned short k_lds[64][ASTR];
  __shared__ __align__(16) unsigned short vt_lds[64][ASTR];
  __shared__ __align__(16) unsigned short p_lds[4][32][ASTR];
  __shared__ float alpha_lds[4][32];
  __shared__ float l_lds[4][32];

  const int tid = threadIdx.x, lane = tid & 63, wave = tid >> 6;
  const int c16 = lane & 15, quad = lane >> 4;
  // swizzle: L = x + 16y + 256z in 0..1023; hb = L&63 pins XCD (mod 8),
  // qt = 15 - (L>>6) makes the first 64 dispatched blocks the heaviest.
  const int L = (int)blockIdx.x + ((int)blockIdx.y << 4) + ((int)blockIdx.z << 8);
  const int h = L & 15, b = (L >> 4) & 3;
  const int qt = 15 - (L >> 6);
  const int qb0 = qt * 128;
  const size_t rkbase = (size_t)b * T_SEQ * DM + (size_t)h * HD;
  const size_t vtbase = (size_t)(b * NH + h) * HD * T_SEQ;

  // Q B-frags (resident): B[n=q][k=d]
  const int q_lo = qb0 + wave * 32;
  bf16x8 qf[2][2];
#pragma unroll
  for (int nf = 0; nf < 2; ++nf) {
    const unsigned short* qp =
        Qw + rkbase + (size_t)(q_lo + nf * 16 + c16) * DM + quad * 8;
    qf[nf][0] = ld8_bf(qp);
    qf[nf][1] = ld8_bf(qp + 32);
  }

  f32x4 o[2][4];
#pragma unroll
  for (int nf = 0; nf < 2; ++nf)
#pragma unroll
    for (int j = 0; j < 4; ++j) o[nf][j] = (f32x4){0.f, 0.f, 0.f, 0.f};
  float m_r[2] = {-3.0e38f, -3.0e38f};
  float l_r[2] = {0.f, 0.f};

  const int srow = tid >> 2;
  const int scol = (tid & 3) * 16;
  const int ntiles = (qb0 + 191) >> 6;
  const int ntiles_w = (q_lo + 95) >> 6;

  // staging pointers (advance per tile)
  const unsigned short* kp = Kw + rkbase + (size_t)srow * DM + scol;
  const unsigned short* vp = Vt + vtbase + (size_t)srow * T_SEQ + scol;
  const size_t kstep = (size_t)64 * DM;

  // prefetch tile 0
  u16x8 ka = *(const u16x8*)kp;
  u16x8 kc = *(const u16x8*)(kp + 8);
  u16x8 va = *(const u16x8*)vp;
  u16x8 vc = *(const u16x8*)(vp + 8);

  for (int t = 0; t < ntiles; ++t) {
    const int kb0 = t * 64;
    __syncthreads();  // previous tile's LDS consumers done
    *(u16x4*)&k_lds[srow][scol]       = lo4(ka);
    *(u16x4*)&k_lds[srow][scol + 4]   = hi4(ka);
    *(u16x4*)&k_lds[srow][scol + 8]   = lo4(kc);
    *(u16x4*)&k_lds[srow][scol + 12]  = hi4(kc);
    *(u16x4*)&vt_lds[srow][scol]      = lo4(va);
    *(u16x4*)&vt_lds[srow][scol + 4]  = hi4(va);
    *(u16x4*)&vt_lds[srow][scol + 8]  = lo4(vc);
    *(u16x4*)&vt_lds[srow][scol + 12] = hi4(vc);
    if (t + 1 < ntiles) {  // issue next tile's loads; waited next iteration
      const unsigned short* kn = kp + (size_t)(t + 1) * kstep;
      const unsigned short* vn = vp + (size_t)(t + 1) * 64;
      ka = *(const u16x8*)kn;
      kc = *(const u16x8*)(kn + 8);
      va = *(const u16x8*)vn;
      vc = *(const u16x8*)(vn + 8);
    }
    __syncthreads();  // staging visible
    if (t >= ntiles_w) continue;

    // ---- S^T = K @ Q^T : D[m=key][n=q] ----
    f32x4 s[4][2];
#pragma unroll
    for (int mf = 0; mf < 4; ++mf) {
      const unsigned short* kr = &k_lds[mf * 16 + c16][quad * 8];
      const bf16x8 k0 = ld8_lds(kr);
      const bf16x8 k1 = ld8_lds(kr + 32);
#pragma unroll
      for (int nf = 0; nf < 2; ++nf) {
        f32x4 a = {0.f, 0.f, 0.f, 0.f};
        a = __builtin_amdgcn_mfma_f32_16x16x32_bf16(k0, qf[nf][0], a, 0, 0, 0);
        a = __builtin_amdgcn_mfma_f32_16x16x32_bf16(k1, qf[nf][1], a, 0, 0, 0);
        s[mf][nf] = a;
      }
    }
    // scale + causal mask: key = kb0+mf*16+quad*4+r, q = q_lo+nf*16+c16
    if (kb0 + 63 > q_lo) {
#pragma unroll
      for (int mf = 0; mf < 4; ++mf) {
        const int key0 = kb0 + mf * 16 + quad * 4;
#pragma unroll
        for (int nf = 0; nf < 2; ++nf) {
          const int qg = q_lo + nf * 16 + c16;
#pragma unroll
          for (int r = 0; r < 4; ++r)
            s[mf][nf][r] =
                (key0 + r <= qg) ? s[mf][nf][r] * 0.125f : -3.0e38f;
        }
      }
    } else {
#pragma unroll
      for (int mf = 0; mf < 4; ++mf)
#pragma unroll
        for (int nf = 0; nf < 2; ++nf)
#pragma unroll
          for (int r = 0; r < 4; ++r) s[mf][nf][r] *= 0.125f;
    }

    // ---- online softmax (per q = column): local 16 + shfl 16,32 ----
#pragma unroll
    for (int nf = 0; nf < 2; ++nf) {
      float mx = -3.0e38f;
#pragma unroll
      for (int mf = 0; mf < 4; ++mf)
#pragma unroll
        for (int r = 0; r < 4; ++r) mx = fmaxf(mx, s[mf][nf][r]);
      mx = fmaxf(mx, __shfl_xor(mx, 16, 64));
      mx = fmaxf(mx, __shfl_xor(mx, 32, 64));
      const float m_new = fmaxf(m_r[nf], mx);
      const float al = __expf(m_r[nf] - m_new);
      m_r[nf] = m_new;
      float ps = 0.f;
#pragma unroll
      for (int mf = 0; mf < 4; ++mf) {
        u16x4 pk;
#pragma unroll
        for (int r = 0; r < 4; ++r) {
          const float e = __expf(s[mf][nf][r] - m_new);
          ps += e;
          pk[r] = f2bf(e);
        }
        *(u16x4*)&p_lds[wave][nf * 16 + c16][mf * 16 + quad * 4] = pk;
      }
      ps += __shfl_xor(ps, 16, 64);
      ps += __shfl_xor(ps, 32, 64);
      l_r[nf] = l_r[nf] * al + ps;
      if (quad == 0) alpha_lds[wave][nf * 16 + c16] = al;
    }
    __threadfence_block();  // drain this wave's LDS writes (p, alpha)

    // ---- rescale O (alpha indexed by row q in C-layout) ----
#pragma unroll
    for (int nf = 0; nf < 2; ++nf) {
      float alr[4];
#pragma unroll
      for (int r = 0; r < 4; ++r)
        alr[r] = alpha_lds[wave][nf * 16 + quad * 4 + r];
#pragma unroll
      for (int j = 0; j < 4; ++j)
#pragma unroll
        for (int r = 0; r < 4; ++r) o[nf][j][r] *= alr[r];
    }

    // ---- O += P @ V : D[m=q][n=d], A=P-frag, B=Vt-frag ----
    bf16x8 pf[2][2];
#pragma unroll
    for (int nf = 0; nf < 2; ++nf) {
      const unsigned short* pw = &p_lds[wave][nf * 16 + c16][quad * 8];
      pf[nf][0] = ld8_lds(pw);
      pf[nf][1] = ld8_lds(pw + 32);
    }
#pragma unroll
    for (int j = 0; j < 4; ++j) {
      const unsigned short* vr = &vt_lds[j * 16 + c16][quad * 8];
      const bf16x8 v0 = ld8_lds(vr);
      const bf16x8 v1 = ld8_lds(vr + 32);
#pragma unroll
      for (int nf = 0; nf < 2; ++nf) {
        o[nf][j] =
            __builtin_amdgcn_mfma_f32_16x16x32_bf16(pf[nf][0], v0, o[nf][j], 0, 0, 0);
        o[nf][j] =
            __builtin_amdgcn_mfma_f32_16x16x32_bf16(pf[nf][1], v1, o[nf][j], 0, 0, 0);
      }
    }
  }

  // ---- epilogue: O/l, C-layout scatter (q = row) ----
  if (quad == 0) {
    l_lds[wave][c16] = l_r[0];
    l_lds[wave][16 + c16] = l_r[1];
  }
  __threadfence_block();
#pragma unroll
  for (int nf = 0; nf < 2; ++nf)
#pragma unroll
    for (int r = 0; r < 4; ++r) {
      const int qg = q_lo + nf * 16 + quad * 4 + r;
      const float inv = 1.0f / l_lds[wave][nf * 16 + quad * 4 + r];
      unsigned short* orow = Ow + rkbase + (size_t)qg * DM;
#pragma unroll
      for (int j = 0; j < 4; ++j)
        orow[j * 16 + c16] = f2bf(o[nf][j][r] * inv);
    }
}

extern "C" void kernel_launch(void* const* d_in, const int* in_sizes, int n_in,
                              void* d_out, int out_size, void* d_ws, size_t ws_size,
                              hipStream_t stream) {
  const float* x_q  = (const float*)d_in[0];
  const float* x_kv = (const float*)d_in[1];
  const float* Wq   = (const float*)d_in[2];
  const float* Wk   = (const float*)d_in[3];
  const float* Wv   = (const float*)d_in[4];
  const float* Wo   = (const float*)d_in[5];
  float* out = (float*)d_out;

  // d_out doubles as early scratch; final GEMM reads only from ws.
  unsigned short* scr  = (unsigned short*)d_out;
  unsigned short* Sx   = scr;                          // x bf16 slot
  unsigned short* Wk_b = scr + (size_t)MROWS * DM;
  unsigned short* Wv_b = Wk_b + (size_t)DM * DM;
  unsigned short* Wq_b = Wv_b + (size_t)DM * DM;

  unsigned short* qb   = (unsigned short*)d_ws;
  unsigned short* kb   = qb + (size_t)MROWS * DM;
  unsigned short* vtb  = kb + (size_t)MROWS * DM;      // Vt[b][h][d][t]
  unsigned short* Wo_b = vtb + (size_t)MROWS * DM;

  const int nW8 = DM * DM / 8;
  const int nX8 = MROWS * DM / 8;

  conv_f32_bf16<<<nW8 / 256, 256, 0, stream>>>(Wk, Wk_b, nW8);
  conv_f32_bf16<<<nW8 / 256, 256, 0, stream>>>(Wv, Wv_b, nW8);
  conv_f32_bf16<<<nW8 / 256, 256, 0, stream>>>(Wq, Wq_b, nW8);
  conv_f32_bf16<<<nW8 / 256, 256, 0, stream>>>(Wo, Wo_b, nW8);
  conv_f32_bf16<<<nX8 / 256, 256, 0, stream>>>(x_kv, Sx, nX8);

  dim3 gg(DM / 128, MROWS / 128);  // (8, 64)
  gemm128<0><<<gg, 256, 0, stream>>>(Sx, Wk_b, kb, MROWS, DM, DM);
  gemm128<2><<<gg, 256, 0, stream>>>(Sx, Wv_b, vtb, MROWS, DM, DM);
  conv_f32_bf16<<<nX8 / 256, 256, 0, stream>>>(x_q, Sx, nX8);
  gemm128<0><<<gg, 256, 0, stream>>>(Sx, Wq_b, qb, MROWS, DM, DM);
  attn_flash3<<<dim3(16, 16, 4), 256, 0, stream>>>(qb, kb, vtb, qb);
  gemm128<1><<<gg, 256, 0, stream>>>(qb, Wo_b, out, MROWS, DM, DM);
}